// Round 10
// baseline (442.493 us; speedup 1.0000x reference)
//
#include <hip/hip_runtime.h>
#include <stdint.h>

typedef unsigned short u16;
typedef __attribute__((ext_vector_type(8))) __bf16 bf16x8;
typedef __attribute__((ext_vector_type(4))) float f32x4;

#define AS1 __attribute__((address_space(1)))
#define AS3 __attribute__((address_space(3)))

__device__ __forceinline__ u16 f2b(float f) {
    union { float f; unsigned u; } v; v.f = f;
    return (u16)((v.u + 0x7fffu + ((v.u >> 16) & 1u)) >> 16);
}

// ---------------------------------------------------------------------------
// fp32 -> bf16 convert, 8 elements/thread. (All 5 inputs proven fp32: R3≡R7.)
// ---------------------------------------------------------------------------
__global__ __launch_bounds__(256) void cvt_kernel(
    const float* __restrict__ src, u16* __restrict__ dst, int n8)
{
    int i = blockIdx.x * 256 + threadIdx.x;
    if (i >= n8) return;
    const float4* s = (const float4*)src;
    float4 f0 = s[(size_t)i * 2], f1 = s[(size_t)i * 2 + 1];
    ushort4 a, b;
    a.x = f2b(f0.x); a.y = f2b(f0.y); a.z = f2b(f0.z); a.w = f2b(f0.w);
    b.x = f2b(f1.x); b.y = f2b(f1.y); b.z = f2b(f1.z); b.w = f2b(f1.w);
    ((ushort4*)dst)[(size_t)i * 2]     = a;
    ((ushort4*)dst)[(size_t)i * 2 + 1] = b;
}

// ---------------------------------------------------------------------------
// GEMM: C[M,N] = A[M,K](bf16) x B[N,K]^T(bf16); m97-style 128x128 tile.
// F32OUT selects fp32 (final output) vs bf16 (intermediates) store.
// ---------------------------------------------------------------------------
template <bool F32OUT>
__device__ __forceinline__ void gemm_tile_body(
    const u16* __restrict__ A, const u16* __restrict__ B, void* __restrict__ Cp,
    int K, int ldc, int mb, int nb, int cb, u16* As, u16* Bs)
{
    const int t  = threadIdx.x;
    const int l  = t & 63, w = t >> 6;
    const int wm = w >> 1, wn = w & 1;
    const int lr = l & 15, lg = l >> 4;

    f32x4 acc[4][4];
#pragma unroll
    for (int i = 0; i < 4; ++i)
#pragma unroll
        for (int j = 0; j < 4; ++j) acc[i][j] = f32x4{0.f, 0.f, 0.f, 0.f};

    for (int k0 = 0; k0 < K; k0 += 32) {
        __syncthreads();
#pragma unroll
        for (int i = 0; i < 2; ++i) {
            int chunk = i * 256 + t;
            int row   = chunk >> 2;
            int c8    = (chunk & 3) << 3;
            const u16* ga = A + (size_t)(mb + row) * K + k0 + c8;
            const u16* gb = B + (size_t)(nb + row) * K + k0 + c8;
            u16* la = As + (i * 256 + w * 64) * 8;   // wave-uniform base; HW adds lane*16
            u16* lb = Bs + (i * 256 + w * 64) * 8;
            __builtin_amdgcn_global_load_lds((AS1 unsigned int*)ga, (AS3 unsigned int*)la, 16, 0, 0);
            __builtin_amdgcn_global_load_lds((AS1 unsigned int*)gb, (AS3 unsigned int*)lb, 16, 0, 0);
        }
        __syncthreads();
        bf16x8 af[4], bfr[4];
#pragma unroll
        for (int mi = 0; mi < 4; ++mi)
            af[mi] = *(const bf16x8*)(As + (wm * 64 + mi * 16 + lr) * 32 + lg * 8);
#pragma unroll
        for (int ni = 0; ni < 4; ++ni)
            bfr[ni] = *(const bf16x8*)(Bs + (wn * 64 + ni * 16 + lr) * 32 + lg * 8);
#pragma unroll
        for (int mi = 0; mi < 4; ++mi)
#pragma unroll
            for (int ni = 0; ni < 4; ++ni)
                acc[mi][ni] = __builtin_amdgcn_mfma_f32_16x16x32_bf16(af[mi], bfr[ni], acc[mi][ni], 0, 0, 0);
    }
    // epilogue: C/D layout col=lane&15, row=(lane>>4)*4+v
#pragma unroll
    for (int mi = 0; mi < 4; ++mi)
#pragma unroll
        for (int ni = 0; ni < 4; ++ni) {
            int col = cb + wn * 64 + ni * 16 + lr;
#pragma unroll
            for (int v = 0; v < 4; ++v) {
                int row = mb + wm * 64 + mi * 16 + lg * 4 + v;
                if (F32OUT)
                    ((float*)Cp)[(size_t)row * ldc + col] = acc[mi][ni][v];
                else
                    ((u16*)Cp)[(size_t)row * ldc + col] = f2b(acc[mi][ni][v]);
            }
        }
}

__global__ __launch_bounds__(256, 2) void gemm_qkv_kernel(
    const u16* __restrict__ X, const u16* __restrict__ W3,  // Wq|Wk|Wv contiguous
    u16* __restrict__ QKV)
{
    __shared__ __attribute__((aligned(16))) u16 As[128 * 32];
    __shared__ __attribute__((aligned(16))) u16 Bs[128 * 32];
    int wsel = blockIdx.y >> 3;
    const u16* B = W3 + (size_t)wsel * 1024 * 1024;
    int nb = (blockIdx.y & 7) * 128;
    gemm_tile_body<false>(X, B, QKV, 1024, 3072, blockIdx.x * 128, nb, wsel * 1024 + nb, As, Bs);
}

__global__ __launch_bounds__(256, 2) void gemm_out_kernel(
    const u16* __restrict__ A, const u16* __restrict__ B, float* __restrict__ C)
{
    __shared__ __attribute__((aligned(16))) u16 As[128 * 32];
    __shared__ __attribute__((aligned(16))) u16 Bs[128 * 32];
    int nb = blockIdx.y * 128;
    gemm_tile_body<true>(A, B, C, 1024, 1024, blockIdx.x * 128, nb, nb, As, Bs);
}

// ---------------------------------------------------------------------------
// Causal flash attention. qkv: [8192,3072] bf16 (Q|K|V col-blocks, head=64).
// One block = (128-row q-tile) x (b,h). BK=64, online softmax, 16x16x32 MFMA.
// ---------------------------------------------------------------------------
#define SEQ  2048
#define PSTR 72

__global__ __launch_bounds__(256, 2) void attn_kernel(
    const u16* __restrict__ qkv, u16* __restrict__ outp)
{
    __shared__ __attribute__((aligned(16))) u16 QP[128 * PSTR];
    __shared__ __attribute__((aligned(16))) u16 Ks[64 * PSTR];
    __shared__ __attribute__((aligned(16))) u16 Vt[64 * PSTR];

    const int t  = threadIdx.x;
    const int l  = t & 63, w = t >> 6;
    const int lr = l & 15, lg = l >> 4;
    const int bh = blockIdx.y;
    const int b  = bh >> 4, h = bh & 15;
    const int qt = (int)gridDim.x - 1 - (int)blockIdx.x;  // longest blocks first
    const int q0 = qt * 128;

    const u16* Qg = qkv + (size_t)b * SEQ * 3072 + h * 64;
    const u16* Kg = Qg + 1024;
    const u16* Vg = Qg + 2048;

#pragma unroll
    for (int i = 0; i < 4; ++i) {
        int r = (t >> 3) + i * 32;
        int c = (t & 7) << 3;
        *(uint4*)(QP + r * PSTR + c) = *(const uint4*)(Qg + (size_t)(q0 + r) * 3072 + c);
    }
    __syncthreads();
    bf16x8 qf[2][2];
#pragma unroll
    for (int mi = 0; mi < 2; ++mi)
#pragma unroll
        for (int ks = 0; ks < 2; ++ks)
            qf[mi][ks] = *(const bf16x8*)(QP + (w * 32 + mi * 16 + lr) * PSTR + ks * 32 + lg * 8);
    __syncthreads();

    f32x4 o[2][4];
#pragma unroll
    for (int mi = 0; mi < 2; ++mi)
#pragma unroll
        for (int nd = 0; nd < 4; ++nd) o[mi][nd] = f32x4{0.f, 0.f, 0.f, 0.f};
    float mrow[2][4], lrow[2][4];
#pragma unroll
    for (int mi = 0; mi < 2; ++mi)
#pragma unroll
        for (int v = 0; v < 4; ++v) { mrow[mi][v] = -__builtin_inff(); lrow[mi][v] = 0.f; }

    const int nkt = 2 * qt + 2;
    for (int kt = 0; kt < nkt; ++kt) {
        const int k0 = kt * 64;
        __syncthreads();
#pragma unroll
        for (int i = 0; i < 2; ++i) {
            int r = (t >> 3) + i * 32;
            int c = (t & 7) << 3;
            *(uint4*)(Ks + r * PSTR + c) = *(const uint4*)(Kg + (size_t)(k0 + r) * 3072 + c);
            uint4 vv = *(const uint4*)(Vg + (size_t)(k0 + r) * 3072 + c);
            Vt[(c + 0) * PSTR + r] = (u16)(vv.x & 0xffff);
            Vt[(c + 1) * PSTR + r] = (u16)(vv.x >> 16);
            Vt[(c + 2) * PSTR + r] = (u16)(vv.y & 0xffff);
            Vt[(c + 3) * PSTR + r] = (u16)(vv.y >> 16);
            Vt[(c + 4) * PSTR + r] = (u16)(vv.z & 0xffff);
            Vt[(c + 5) * PSTR + r] = (u16)(vv.z >> 16);
            Vt[(c + 6) * PSTR + r] = (u16)(vv.w & 0xffff);
            Vt[(c + 7) * PSTR + r] = (u16)(vv.w >> 16);
        }
        __syncthreads();

        f32x4 s[2][4];
#pragma unroll
        for (int mi = 0; mi < 2; ++mi)
#pragma unroll
            for (int ni = 0; ni < 4; ++ni) s[mi][ni] = f32x4{0.f, 0.f, 0.f, 0.f};
#pragma unroll
        for (int ks = 0; ks < 2; ++ks) {
            bf16x8 kb[4];
#pragma unroll
            for (int ni = 0; ni < 4; ++ni)
                kb[ni] = *(const bf16x8*)(Ks + (ni * 16 + lr) * PSTR + ks * 32 + lg * 8);
#pragma unroll
            for (int mi = 0; mi < 2; ++mi)
#pragma unroll
                for (int ni = 0; ni < 4; ++ni)
                    s[mi][ni] = __builtin_amdgcn_mfma_f32_16x16x32_bf16(qf[mi][ks], kb[ni], s[mi][ni], 0, 0, 0);
        }

        const bool domask = (k0 + 63) > (q0 + w * 32);
#pragma unroll
        for (int mi = 0; mi < 2; ++mi)
#pragma unroll
            for (int ni = 0; ni < 4; ++ni)
#pragma unroll
                for (int v = 0; v < 4; ++v) {
                    float x = s[mi][ni][v] * 0.125f;
                    if (domask) {
                        int qpos = q0 + w * 32 + mi * 16 + lg * 4 + v;
                        int kpos = k0 + ni * 16 + lr;
                        if (kpos > qpos) x = -__builtin_inff();
                    }
                    s[mi][ni][v] = x;
                }

#pragma unroll
        for (int mi = 0; mi < 2; ++mi)
#pragma unroll
            for (int v = 0; v < 4; ++v) {
                float r = fmaxf(fmaxf(s[mi][0][v], s[mi][1][v]), fmaxf(s[mi][2][v], s[mi][3][v]));
                r = fmaxf(r, __shfl_xor(r, 1));
                r = fmaxf(r, __shfl_xor(r, 2));
                r = fmaxf(r, __shfl_xor(r, 4));
                r = fmaxf(r, __shfl_xor(r, 8));
                float mn = fmaxf(mrow[mi][v], r);
                float al = __expf(mrow[mi][v] - mn);
                mrow[mi][v] = mn;
                float sum = 0.f;
#pragma unroll
                for (int ni = 0; ni < 4; ++ni) {
                    float p = __expf(s[mi][ni][v] - mn);
                    s[mi][ni][v] = p;
                    sum += p;
                }
                sum += __shfl_xor(sum, 1);
                sum += __shfl_xor(sum, 2);
                sum += __shfl_xor(sum, 4);
                sum += __shfl_xor(sum, 8);
                lrow[mi][v] = lrow[mi][v] * al + sum;
#pragma unroll
                for (int nd = 0; nd < 4; ++nd) o[mi][nd][v] *= al;
            }

#pragma unroll
        for (int mi = 0; mi < 2; ++mi)
#pragma unroll
            for (int ni = 0; ni < 4; ++ni)
#pragma unroll
                for (int v = 0; v < 4; ++v)
                    QP[(w * 32 + mi * 16 + lg * 4 + v) * PSTR + ni * 16 + lr] = f2b(s[mi][ni][v]);

#pragma unroll
        for (int ks = 0; ks < 2; ++ks) {
            bf16x8 pa[2], vb[4];
#pragma unroll
            for (int mi = 0; mi < 2; ++mi)
                pa[mi] = *(const bf16x8*)(QP + (w * 32 + mi * 16 + lr) * PSTR + ks * 32 + lg * 8);
#pragma unroll
            for (int nd = 0; nd < 4; ++nd)
                vb[nd] = *(const bf16x8*)(Vt + (nd * 16 + lr) * PSTR + ks * 32 + lg * 8);
#pragma unroll
            for (int mi = 0; mi < 2; ++mi)
#pragma unroll
                for (int nd = 0; nd < 4; ++nd)
                    o[mi][nd] = __builtin_amdgcn_mfma_f32_16x16x32_bf16(pa[mi], vb[nd], o[mi][nd], 0, 0, 0);
        }
    }

#pragma unroll
    for (int mi = 0; mi < 2; ++mi)
#pragma unroll
        for (int v = 0; v < 4; ++v) {
            float inv = 1.f / lrow[mi][v];
            int row = q0 + w * 32 + mi * 16 + lg * 4 + v;
#pragma unroll
            for (int nd = 0; nd < 4; ++nd) {
                int col = h * 64 + nd * 16 + lr;
                outp[(size_t)(b * SEQ + row) * 1024 + col] = f2b(o[mi][nd][v] * inv);
            }
        }
}

// ---------------------------------------------------------------------------
extern "C" void kernel_launch(void* const* d_in, const int* in_sizes, int n_in,
                              void* d_out, int out_size, void* d_ws, size_t ws_size,
                              hipStream_t stream)
{
    (void)in_sizes; (void)n_in; (void)out_size; (void)ws_size;
    const float* x  = (const float*)d_in[0];
    const float* Wq = (const float*)d_in[1];
    const float* Wk = (const float*)d_in[2];
    const float* Wv = (const float*)d_in[3];
    const float* Wo = (const float*)d_in[4];

    // ws: qkv bf16 48 MB + xb/att bf16 16 MB (aliased) = 64 MB.
    // d_out (33.5 MB fp32) doubles as pre-final scratch for Wq|Wk|Wv bf16
    // (first 6 MB, dead before the final fp32 store overwrites d_out).
    u16*   qkv = (u16*)d_ws;                     // [8192,3072] bf16
    u16*   xb  = qkv + (size_t)8192 * 3072;      // [8192,1024] bf16
    u16*   att = xb;                             // alias: xb dead after QKV GEMM
    u16*   w3  = (u16*)d_out;                    // Wq|Wk|Wv bf16 scratch
    u16*   wob = qkv;                            // Wo bf16 -> dead qkv region
    float* out = (float*)d_out;                  // final [8192,1024] fp32

    cvt_kernel<<<dim3(4096), 256, 0, stream>>>(x,  xb,              1048576);  // x
    cvt_kernel<<<dim3(512),  256, 0, stream>>>(Wq, w3,              131072);
    cvt_kernel<<<dim3(512),  256, 0, stream>>>(Wk, w3 + (1u << 20), 131072);
    cvt_kernel<<<dim3(512),  256, 0, stream>>>(Wv, w3 + (2u << 20), 131072);

    gemm_qkv_kernel<<<dim3(64, 24), 256, 0, stream>>>(xb, w3, qkv);
    attn_kernel   <<<dim3(16, 64), 256, 0, stream>>>(qkv, att);

    cvt_kernel<<<dim3(512), 256, 0, stream>>>(Wo, wob, 131072);                // Wo
    gemm_out_kernel<<<dim3(64, 8), 256, 0, stream>>>(att, wob, out);
}